// Round 1
// baseline (146.640 us; speedup 1.0000x reference)
//
#include <hip/hip_runtime.h>

// TwelveSitesNN2 R12: occupancy unlock + VALU->MFMA shift.
//  (1) w2T B-fragments moved from 48 prefetch VGPRs to an LDS stage (13.3KB,
//      loaded before layer 1, read per-section in layer 2) -> unified regs ~95.
//  (2) layer 2 as 9-tap circulant: per tap ds_read_b128 -> MFMA directly
//      (no f16 add-trees; 108 MFMA/wave on the idle matrix pipe).
//  (3) layer 1 per-site loop (no xr/xA/xB arrays; -72 live regs at peak).
//  (4) __launch_bounds__(256,5): 5 blocks/CU (LDS 29952B -> exactly 5).

#define LNUM 63
#define BT 16
#define NBT 128   // 2048 / BT
#define WSL 19968 // ushorts per l in ws: [w2T 64x104][fw1T 64x136][fw2T 64x72] (f16)

typedef __attribute__((ext_vector_type(8))) _Float16 half8;
typedef __attribute__((ext_vector_type(2))) _Float16 half2v;
typedef __attribute__((ext_vector_type(4))) float floatx4;
typedef __attribute__((ext_vector_type(4))) unsigned uint4v;

static __device__ __forceinline__ unsigned cvtpk(float a, float b) {
    return __builtin_bit_cast(unsigned, __builtin_amdgcn_cvt_pkrtz(a, b));  // 1 VALU op
}
static __device__ __forceinline__ half2v u2h(unsigned u) { return __builtin_bit_cast(half2v, u); }
static __device__ __forceinline__ float hlo16(unsigned short s) {
    return (float)__builtin_bit_cast(_Float16, s);
}
static __device__ __forceinline__ int w12(int v) { return v >= 12 ? v - 12 : v; }
static __device__ __forceinline__ float2 add2(float2 a, float2 b) { return make_float2(a.x + b.x, a.y + b.y); }

// LDS layout of fused_nn, dword units (U: 7488 dw = 29952 B):
//   phase1 : h1 [192 rows][20 dw] (16 used: 32 f16 ch; cols 16-19 pad)   @0
//   persistent: W2LDS [832 uint4] = w2T f16 [o=64][52 dw]                @4160
//   phase2 : PART [1024 u=(b*64+ch)][3 chunks] (f16 sum,max per dword)    @0 (overlay)
//            POOLED [16 b][68 dw] (k'-interleaved mean/max f16)           @3072
//   phase3 : POOL2 ush@0 [16][72], G2 ush@1280 [16][72] (overlay PART)
#define O_W2DW   4160
#define O_POOLDW 3072
#define O_POOLUS 6144
#define O_POOL2  0
#define O_G2     1280

// prep: grid (LNUM, 3), coalesced float4 reads -> LDS transpose -> coalesced
// dword writes. Region 0: w2T [o][52dw]; 1: fw1T [o][68dw] k'-interleaved;
// 2: fw2T [o][36dw].   (unchanged from R11)
__global__ void prep(const float* __restrict__ w2, const float* __restrict__ fw1,
                     const float* __restrict__ fw2, unsigned short* __restrict__ ws) {
    __shared__ float S[8192];
    const int l = blockIdx.x, r = blockIdx.y, t = threadIdx.x;
    if (r == 0) {
        const float4* src = (const float4*)(w2 + (size_t)l * 6144);   // [96][64]
        #pragma unroll
        for (int j = 0; j < 6; ++j) *(float4*)(S + 4 * (t + 256 * j)) = src[t + 256 * j];
        __syncthreads();
        unsigned* dst = (unsigned*)(ws + (size_t)l * WSL);            // 3328 dw
        #pragma unroll
        for (int j = 0; j < 13; ++j) {
            int i = j * 256 + t, o = i / 52, cp = i - 52 * o, c = 2 * cp;
            dst[i] = cvtpk(S[c * 64 + o], S[c * 64 + 64 + o]);
        }
    } else if (r == 1) {
        const float4* src = (const float4*)(fw1 + (size_t)l * 8192);  // [128][64]
        #pragma unroll
        for (int j = 0; j < 8; ++j) *(float4*)(S + 4 * (t + 256 * j)) = src[t + 256 * j];
        __syncthreads();
        unsigned* dst = (unsigned*)(ws + (size_t)l * WSL + 6656);     // 4352 dw
        #pragma unroll
        for (int j = 0; j < 17; ++j) {
            int i = j * 256 + t, o = i / 68, cp = i - 68 * o;
            dst[i] = cvtpk(S[cp * 64 + o], S[(64 + cp) * 64 + o]);    // k'-interleave
        }
    } else {
        const float4* src = (const float4*)(fw2 + (size_t)l * 4096);  // [64][64]
        #pragma unroll
        for (int j = 0; j < 4; ++j) *(float4*)(S + 4 * (t + 256 * j)) = src[t + 256 * j];
        __syncthreads();
        unsigned* dst = (unsigned*)(ws + (size_t)l * WSL + 15360);    // 2304 dw
        #pragma unroll
        for (int j = 0; j < 9; ++j) {
            int i = j * 256 + t, o = i / 36, cp = i - 36 * o, c = 2 * cp;
            dst[i] = cvtpk(S[c * 64 + o], S[c * 64 + 64 + o]);
        }
    }
}

__global__ __launch_bounds__(256, 5) void fused_nn(
    const float* __restrict__ zs,  const float* __restrict__ w1,
    const float* __restrict__ fb1, const float* __restrict__ fb2,
    const float* __restrict__ fw3, const float* __restrict__ fb3,
    const unsigned short* __restrict__ ws,
    float* __restrict__ out)
{
    __shared__ __align__(16) unsigned U[7488];
    unsigned short* USH = (unsigned short*)U;

    const int t    = threadIdx.x;
    const int lane = t & 63;
    const int wv   = t >> 6;
    const int n    = lane & 15;
    const int quad = lane >> 4;
    const int l    = blockIdx.x / NBT;
    const int b0   = (blockIdx.x % NBT) * BT;

    // ---------------- stage w2T (13312 B) global -> LDS, overlapped with layer 1 ----
    // 832 uint4: 3 full rounds (256 thr) + partial round (t < 64).
    {
        const uint4v* src = (const uint4v*)(ws + (size_t)l * WSL);
        uint4v s0 = src[t];
        uint4v s1 = src[t + 256];
        uint4v s2 = src[t + 512];
        uint4v s3 = (t < 64) ? src[t + 768] : (uint4v){0, 0, 0, 0};
        uint4v* dst = (uint4v*)(U + O_W2DW);
        dst[t]       = s0;
        dst[t + 256] = s1;
        dst[t + 512] = s2;
        if (t < 64) dst[t + 768] = s3;
    }

    // ---------------- layer 1, thread-local, per-site (low reg); write h1 ----------
    {
        const int b = t >> 4, cpair = t & 15, c0 = cpair * 2;
        const float* xb = zs + ((size_t)(b0 + b) * LNUM + l) * 24;
        float2 xv[12];
        #pragma unroll
        for (int q = 0; q < 6; ++q) {
            float4 xq = *(const float4*)(xb + q * 4);
            xv[2 * q]     = make_float2(xq.x, xq.y);
            xv[2 * q + 1] = make_float2(xq.z, xq.w);
        }
        const float* wl = w1 + (size_t)l * 192 + c0;
        const float2 w0  = *(const float2*)(wl);
        const float2 w1v = *(const float2*)(wl + 32);
        const float2 w2v = *(const float2*)(wl + 64);
        const float2 w3v = *(const float2*)(wl + 96);
        const float2 w4v = *(const float2*)(wl + 128);
        const float2 w5v = *(const float2*)(wl + 160);
        #pragma unroll
        for (int s = 0; s < 12; ++s) {
            // xA = sum of x at s+-1, s+-3 ; xB = sum of x at s+-2, s+-4 (mod 12)
            float2 xA = add2(add2(xv[w12(s + 1)], xv[w12(s + 11)]),
                             add2(xv[w12(s + 3)], xv[w12(s + 9)]));
            float2 xB = add2(add2(xv[w12(s + 2)], xv[w12(s + 10)]),
                             add2(xv[w12(s + 4)], xv[w12(s + 8)]));
            float hx = xv[s].x*w0.x + xv[s].y*w1v.x + xA.x*w2v.x + xA.y*w3v.x
                     + xB.x*w4v.x + xB.y*w5v.x;
            float hy = xv[s].x*w0.y + xv[s].y*w1v.y + xA.x*w2v.y + xA.y*w3v.y
                     + xB.x*w4v.y + xB.y*w5v.y;
            U[(b * 12 + s) * 20 + cpair] = cvtpk(fmaxf(hx, 0.f), fmaxf(hy, 0.f));
        }
    }
    // hoist fc bias loads (hide VMEM latency behind layer 2)
    const float bias1 = fb1[(size_t)l * 64 + wv * 16 + n];
    const float bias2 = fb2[(size_t)l * 64 + wv * 16 + n];
    __syncthreads();   // h1 ready AND W2LDS ready (vmcnt/lgkm drained at barrier)

    // ---------------- layer 2: 9-tap circulant MFMA (M=192,N=64), B from LDS ------
    floatx4 acc[3][4];
    #pragma unroll
    for (int mi = 0; mi < 3; ++mi)
        #pragma unroll
        for (int nt = 0; nt < 4; ++nt) acc[mi][nt] = (floatx4){0.f, 0.f, 0.f, 0.f};
    {
        int rbq[3], a20[3];
        #pragma unroll
        for (int mi = 0; mi < 3; ++mi) {
            int row = 48 * wv + 16 * mi + n;
            int bi = row / 12;
            int si = row - 12 * bi;
            rbq[mi] = bi * 240 + quad * 4;   // (bi*12)*20 + quad*4
            a20[mi] = si * 20;
        }
        const uint4v* w2l = (const uint4v*)(U + O_W2DW);
        const int c13 = n * 13 + quad;       // per-lane uint4 base within a section
        // taps: sec0 = {0}, sec1 = {1,11,3,9}, sec2 = {2,10,4,8}
        constexpr int tapd[9] = {0, 1, 11, 3, 9, 2, 10, 4, 8};
        uint4v bw[4];
        #pragma unroll
        for (int i = 0; i < 9; ++i) {
            const int sec = (i == 0) ? 0 : (i < 5 ? 1 : 2);
            if (i == 0 || i == 1 || i == 5) {
                #pragma unroll
                for (int nt = 0; nt < 4; ++nt)
                    bw[nt] = w2l[c13 + nt * 208 + sec * 4];
            }
            half8 af[3];
            #pragma unroll
            for (int mi = 0; mi < 3; ++mi) {
                int off = a20[mi] + tapd[i] * 20;
                if (tapd[i]) { if (off >= 240) off -= 240; }   // w12 wrap (off < 480)
                af[mi] = *(const half8*)(U + rbq[mi] + off);
            }
            #pragma unroll
            for (int mi = 0; mi < 3; ++mi)
                #pragma unroll
                for (int nt = 0; nt < 4; ++nt)
                    acc[mi][nt] = __builtin_amdgcn_mfma_f32_16x16x32_f16(
                        af[mi], __builtin_bit_cast(half8, bw[nt]), acc[mi][nt], 0, 0, 0);
        }
    }
    __syncthreads();   // h1 reads done -> PART overlays

    // ---------------- register pool partials: relu + sum4/max4 -> PART ----------------
    #pragma unroll
    for (int mi = 0; mi < 3; ++mi) {
        const int rr = 48 * wv + 16 * mi + 4 * quad;   // 4 rows, all within one b
        const int bq = rr / 12;
        const int chk = (rr - 12 * bq) >> 2;
        #pragma unroll
        for (int nt = 0; nt < 4; ++nt) {
            const int ch = nt * 16 + n;
            float r0 = fmaxf(acc[mi][nt][0], 0.f), r1 = fmaxf(acc[mi][nt][1], 0.f);
            float r2 = fmaxf(acc[mi][nt][2], 0.f), r3 = fmaxf(acc[mi][nt][3], 0.f);
            float sm = (r0 + r1) + (r2 + r3);
            float mx = fmaxf(fmaxf(r0, r1), fmaxf(r2, r3));
            U[(bq * 64 + ch) * 3 + chk] = cvtpk(sm, mx);
        }
    }
    // PART write->read is intra-wave (writer b-range 4wv..4wv+3 == reader b = t>>4):
    // DS ops complete in order per wave; only prevent compiler reordering.
    __builtin_amdgcn_wave_barrier();

    // ---------------- pool-final: 3 b128 reads, f16 combine -> POOLED ----------------
    {
        const unsigned* p = U + t * 12;                // units 4t..4t+3
        uint4v q0 = *(const uint4v*)(p);
        uint4v q1 = *(const uint4v*)(p + 4);
        uint4v q2 = *(const uint4v*)(p + 8);
        unsigned arr[12] = {q0.x, q0.y, q0.z, q0.w, q1.x, q1.y, q1.z, q1.w,
                            q2.x, q2.y, q2.z, q2.w};
        const int b = t >> 4, ch0 = (t * 4) & 63;
        const _Float16 inv12 = (_Float16)(1.0f / 12.0f);
        unsigned pk[4];
        #pragma unroll
        for (int j = 0; j < 4; ++j) {
            half2v d0 = u2h(arr[3 * j]), d1 = u2h(arr[3 * j + 1]), d2 = u2h(arr[3 * j + 2]);
            _Float16 s = (d0[0] + d1[0]) + d2[0];
            _Float16 m0 = d0[1] > d1[1] ? d0[1] : d1[1];
            _Float16 m  = m0 > d2[1] ? m0 : d2[1];
            half2v pm;
            pm[0] = s * inv12;
            pm[1] = m;
            pk[j] = __builtin_bit_cast(unsigned, pm);
        }
        uint2 w01 = make_uint2(pk[0], pk[1]), w23 = make_uint2(pk[2], pk[3]);
        *(uint2*)(U + O_POOLDW + b * 68 + ch0)     = w01;
        *(uint2*)(U + O_POOLDW + b * 68 + ch0 + 2) = w23;
    }
    __syncthreads();

    // ---------------- fc1: MFMA (M=16, K=128, N=64), B from ws (k'-reordered) ----------------
    {
        const int o = wv * 16 + n;
        floatx4 a1 = (floatx4){bias1, bias1, bias1, bias1};
        const uint4v* f1q = (const uint4v*)(ws + (size_t)l * WSL + 6656);
        #pragma unroll
        for (int ks = 0; ks < 4; ++ks) {
            half8 av = *(const half8*)(USH + O_POOLUS + n * 136 + ks * 32 + quad * 8);
            uint4v bw = f1q[o * 17 + ks * 4 + quad];
            a1 = __builtin_amdgcn_mfma_f32_16x16x32_f16(av, __builtin_bit_cast(half8, bw), a1, 0, 0, 0);
        }
        #pragma unroll
        for (int i = 0; i < 2; ++i) {
            unsigned pk = cvtpk(fmaxf(a1[2 * i], 0.f), fmaxf(a1[2 * i + 1], 0.f));
            USH[O_POOL2 + (quad * 4 + 2 * i)     * 72 + o] = (unsigned short)(pk & 0xffffu);
            USH[O_POOL2 + (quad * 4 + 2 * i + 1) * 72 + o] = (unsigned short)(pk >> 16);
        }
    }
    __syncthreads();

    // ---------------- fc2: MFMA (M=16, K=64, N=64), B from ws ----------------
    {
        const int o = wv * 16 + n;
        floatx4 a2 = (floatx4){bias2, bias2, bias2, bias2};
        const uint4v* f2q = (const uint4v*)(ws + (size_t)l * WSL + 15360);
        #pragma unroll
        for (int ks = 0; ks < 2; ++ks) {
            half8 av = *(const half8*)(USH + O_POOL2 + n * 72 + ks * 32 + quad * 8);
            uint4v bw = f2q[o * 9 + ks * 4 + quad];
            a2 = __builtin_amdgcn_mfma_f32_16x16x32_f16(av, __builtin_bit_cast(half8, bw), a2, 0, 0, 0);
        }
        #pragma unroll
        for (int i = 0; i < 2; ++i) {
            unsigned pk = cvtpk(fmaxf(a2[2 * i], 0.f), fmaxf(a2[2 * i + 1], 0.f));
            USH[O_G2 + (quad * 4 + 2 * i)     * 72 + o] = (unsigned short)(pk & 0xffffu);
            USH[O_G2 + (quad * 4 + 2 * i + 1) * 72 + o] = (unsigned short)(pk >> 16);
        }
    }
    __syncthreads();

    // ---------------- fc3 (K=64) + output ----------------
    if (t < 16) {
        float a = fb3[l];
        const float* w3 = fw3 + (size_t)l * 64;
        #pragma unroll
        for (int c4 = 0; c4 < 16; ++c4) {
            uint2 u2 = *(const uint2*)(USH + O_G2 + t * 72 + c4 * 4);
            float4 w = *(const float4*)(w3 + c4 * 4);
            a += hlo16((unsigned short)(u2.x & 0xffff)) * w.x
               + hlo16((unsigned short)(u2.x >> 16))    * w.y
               + hlo16((unsigned short)(u2.y & 0xffff)) * w.z
               + hlo16((unsigned short)(u2.y >> 16))    * w.w;
        }
        out[(size_t)(b0 + t) * LNUM + l] = a;
    }
}

extern "C" void kernel_launch(void* const* d_in, const int* in_sizes, int n_in,
                              void* d_out, int out_size, void* d_ws, size_t ws_size,
                              hipStream_t stream) {
    const float* zs  = (const float*)d_in[0];
    const float* w1  = (const float*)d_in[1];
    const float* w2  = (const float*)d_in[2];
    const float* fw1 = (const float*)d_in[3];
    const float* fb1 = (const float*)d_in[4];
    const float* fw2 = (const float*)d_in[5];
    const float* fb2 = (const float*)d_in[6];
    const float* fw3 = (const float*)d_in[7];
    const float* fb3 = (const float*)d_in[8];
    float* out = (float*)d_out;
    unsigned short* ws = (unsigned short*)d_ws;

    hipLaunchKernelGGL(prep, dim3(LNUM, 3), dim3(256), 0, stream, w2, fw1, fw2, ws);
    hipLaunchKernelGGL(fused_nn, dim3(LNUM * NBT), dim3(256), 0, stream,
                       zs, w1, fb1, fb2, fw3, fb3, ws, out);
}

// Round 2
// 138.990 us; speedup vs baseline: 1.0550x; 1.0550x over previous
//
#include <hip/hip_runtime.h>

// TwelveSitesNN2 R13: unbundle R12 + amortize per-block fixed cost 2x.
//  - revert 9-tap -> R11 add-tree layer 2 (36 MFMA/wave, matrix work back to min)
//  - keep w2T LDS staging (no 48-reg prefetch) and per-site layer 1
//  - BT 16 -> 32, 512-thread (8-wave) blocks: staging bytes, barriers and
//    fc1/fc2/fc3 phase latency per batch-element all halve; fc uses 8 waves
//    (M=32: 2 M-tiles x 4 N-tiles, one 16x16 tile per wave)
//  - __launch_bounds__(512,4): regs capped 128 -> no spills (R12 lesson),
//    2 blocks/CU (16 waves), LDS 44032 B

#define LNUM 63
#define BT 32
#define NBT 64    // 2048 / BT
#define WSL 19968 // ushorts per l in ws: [w2T 64x104][fw1T 64x136][fw2T 64x72] (f16)

typedef __attribute__((ext_vector_type(8))) _Float16 half8;
typedef __attribute__((ext_vector_type(2))) _Float16 half2v;
typedef __attribute__((ext_vector_type(4))) float floatx4;
typedef __attribute__((ext_vector_type(4))) unsigned uint4v;

static __device__ __forceinline__ unsigned cvtpk(float a, float b) {
    return __builtin_bit_cast(unsigned, __builtin_amdgcn_cvt_pkrtz(a, b));  // 1 VALU op
}
static __device__ __forceinline__ half2v u2h(unsigned u) { return __builtin_bit_cast(half2v, u); }
static __device__ __forceinline__ float hlo16(unsigned short s) {
    return (float)__builtin_bit_cast(_Float16, s);
}
static __device__ __forceinline__ int w12(int v) { return v >= 12 ? v - 12 : v; }
static __device__ __forceinline__ float2 add2(float2 a, float2 b) { return make_float2(a.x + b.x, a.y + b.y); }

// LDS layout of fused_nn, dword units (U: 11008 dw = 44032 B):
//   phase1 : h1 [384 rows][20 dw] (16 used: 32 f16 ch; cols 16-19 pad)   @0
//   persistent: W2LDS [832 uint4] = w2T f16 [o=64][52 dw]                @7680
//   phase2 : PART [2048 u=(b*64+ch)][3 chunks] (f16 sum,max per dword)    @0 (overlay h1)
//            POOLED [32 b][68 dw] (k'-interleaved mean/max f16)           @7680 (overlay W2)
//   phase3 : POOL2 ush@0 [32][72], G2 ush@2304 [32][72] (overlay PART)
#define O_W2DW   7680
#define O_POOLDW 7680
#define O_POOLUS 15360
#define O_POOL2  0
#define O_G2     2304

// prep: grid (LNUM, 3), coalesced float4 reads -> LDS transpose -> coalesced
// dword writes. Region 0: w2T [o][52dw]; 1: fw1T [o][68dw] k'-interleaved;
// 2: fw2T [o][36dw].   (unchanged)
__global__ void prep(const float* __restrict__ w2, const float* __restrict__ fw1,
                     const float* __restrict__ fw2, unsigned short* __restrict__ ws) {
    __shared__ float S[8192];
    const int l = blockIdx.x, r = blockIdx.y, t = threadIdx.x;
    if (r == 0) {
        const float4* src = (const float4*)(w2 + (size_t)l * 6144);   // [96][64]
        #pragma unroll
        for (int j = 0; j < 6; ++j) *(float4*)(S + 4 * (t + 256 * j)) = src[t + 256 * j];
        __syncthreads();
        unsigned* dst = (unsigned*)(ws + (size_t)l * WSL);            // 3328 dw
        #pragma unroll
        for (int j = 0; j < 13; ++j) {
            int i = j * 256 + t, o = i / 52, cp = i - 52 * o, c = 2 * cp;
            dst[i] = cvtpk(S[c * 64 + o], S[c * 64 + 64 + o]);
        }
    } else if (r == 1) {
        const float4* src = (const float4*)(fw1 + (size_t)l * 8192);  // [128][64]
        #pragma unroll
        for (int j = 0; j < 8; ++j) *(float4*)(S + 4 * (t + 256 * j)) = src[t + 256 * j];
        __syncthreads();
        unsigned* dst = (unsigned*)(ws + (size_t)l * WSL + 6656);     // 4352 dw
        #pragma unroll
        for (int j = 0; j < 17; ++j) {
            int i = j * 256 + t, o = i / 68, cp = i - 68 * o;
            dst[i] = cvtpk(S[cp * 64 + o], S[(64 + cp) * 64 + o]);    // k'-interleave
        }
    } else {
        const float4* src = (const float4*)(fw2 + (size_t)l * 4096);  // [64][64]
        #pragma unroll
        for (int j = 0; j < 4; ++j) *(float4*)(S + 4 * (t + 256 * j)) = src[t + 256 * j];
        __syncthreads();
        unsigned* dst = (unsigned*)(ws + (size_t)l * WSL + 15360);    // 2304 dw
        #pragma unroll
        for (int j = 0; j < 9; ++j) {
            int i = j * 256 + t, o = i / 36, cp = i - 36 * o, c = 2 * cp;
            dst[i] = cvtpk(S[c * 64 + o], S[c * 64 + 64 + o]);
        }
    }
}

__global__ __launch_bounds__(512, 4) void fused_nn(
    const float* __restrict__ zs,  const float* __restrict__ w1,
    const float* __restrict__ fb1, const float* __restrict__ fb2,
    const float* __restrict__ fw3, const float* __restrict__ fb3,
    const unsigned short* __restrict__ ws,
    float* __restrict__ out)
{
    __shared__ __align__(16) unsigned U[11008];
    unsigned short* USH = (unsigned short*)U;

    const int t    = threadIdx.x;
    const int lane = t & 63;
    const int wv   = t >> 6;           // 0..7
    const int n    = lane & 15;
    const int quad = lane >> 4;
    const int l    = blockIdx.x / NBT;
    const int b0   = (blockIdx.x % NBT) * BT;

    // ---------------- stage w2T (13312 B) global -> LDS, overlapped with layer 1 ----
    // 832 uint4 over 512 threads: 1 full round + partial (t < 320).
    {
        const uint4v* src = (const uint4v*)(ws + (size_t)l * WSL);
        uint4v* dst = (uint4v*)(U + O_W2DW);
        uint4v s0 = src[t];
        if (t < 320) {
            uint4v s1 = src[512 + t];
            dst[t] = s0;
            dst[512 + t] = s1;
        } else {
            dst[t] = s0;
        }
    }

    // ---------------- layer 1, thread-local, per-site (low reg); write h1 ----------
    {
        const int b = t >> 4, cpair = t & 15, c0 = cpair * 2;   // b: 0..31
        const float* xb = zs + ((size_t)(b0 + b) * LNUM + l) * 24;
        float2 xv[12];
        #pragma unroll
        for (int q = 0; q < 6; ++q) {
            float4 xq = *(const float4*)(xb + q * 4);
            xv[2 * q]     = make_float2(xq.x, xq.y);
            xv[2 * q + 1] = make_float2(xq.z, xq.w);
        }
        const float* wl = w1 + (size_t)l * 192 + c0;
        const float2 w0  = *(const float2*)(wl);
        const float2 w1v = *(const float2*)(wl + 32);
        const float2 w2v = *(const float2*)(wl + 64);
        const float2 w3v = *(const float2*)(wl + 96);
        const float2 w4v = *(const float2*)(wl + 128);
        const float2 w5v = *(const float2*)(wl + 160);
        #pragma unroll
        for (int s = 0; s < 12; ++s) {
            // xA = sum of x at s+-1, s+-3 ; xB = sum of x at s+-2, s+-4 (mod 12)
            float2 xA = add2(add2(xv[w12(s + 1)], xv[w12(s + 11)]),
                             add2(xv[w12(s + 3)], xv[w12(s + 9)]));
            float2 xB = add2(add2(xv[w12(s + 2)], xv[w12(s + 10)]),
                             add2(xv[w12(s + 4)], xv[w12(s + 8)]));
            float hx = xv[s].x*w0.x + xv[s].y*w1v.x + xA.x*w2v.x + xA.y*w3v.x
                     + xB.x*w4v.x + xB.y*w5v.x;
            float hy = xv[s].x*w0.y + xv[s].y*w1v.y + xA.x*w2v.y + xA.y*w3v.y
                     + xB.x*w4v.y + xB.y*w5v.y;
            U[(b * 12 + s) * 20 + cpair] = cvtpk(fmaxf(hx, 0.f), fmaxf(hy, 0.f));
        }
    }
    // fc tiles: wave wv -> M-tile mt (batch rows 16mt..16mt+15), N-tile (wv&3)
    const int mt = wv >> 2;
    const int oc = (wv & 3) * 16 + n;      // fc output channel for this lane
    // hoist fc bias loads (hide VMEM latency behind layer 2)
    const float bias1 = fb1[(size_t)l * 64 + oc];
    const float bias2 = fb2[(size_t)l * 64 + oc];
    __syncthreads();   // h1 ready AND W2LDS ready

    // ---------------- layer 2: MFMA f16 (M=384,K=96,N=64); add-tree A, B from LDS --
    floatx4 acc[3][4];
    #pragma unroll
    for (int mi = 0; mi < 3; ++mi)
        #pragma unroll
        for (int nt = 0; nt < 4; ++nt) acc[mi][nt] = (floatx4){0.f, 0.f, 0.f, 0.f};
    {
        int rbq[3], si_[3];
        #pragma unroll
        for (int mi = 0; mi < 3; ++mi) {
            int rowm = 16 * mi + n;            // 48*wv divisible by 12
            int bi = 4 * wv + rowm / 12;
            si_[mi] = rowm % 12;
            rbq[mi] = bi * 240 + quad * 4;     // (bi*12)*20 + quad*4
        }
        const uint4v* w2l = (const uint4v*)(U + O_W2DW);
        const int c13 = n * 13 + quad;         // per-lane uint4 base within a row
        const int dA[4] = {1, 11, 3, 9};
        const int dB[4] = {2, 10, 4, 8};
        #pragma unroll
        for (int ks = 0; ks < 3; ++ks) {
            uint4v bw[4];
            #pragma unroll
            for (int nt = 0; nt < 4; ++nt)
                bw[nt] = w2l[c13 + nt * 208 + ks * 4];
            half8 af[3];
            #pragma unroll
            for (int mi = 0; mi < 3; ++mi) {
                const int s = si_[mi], base = rbq[mi];
                if (ks == 0) {
                    af[mi] = *(const half8*)(U + base + s * 20);
                } else {
                    const int* d = (ks == 1) ? dA : dB;
                    half8 l0 = *(const half8*)(U + base + w12(s + d[0]) * 20);
                    half8 l1 = *(const half8*)(U + base + w12(s + d[1]) * 20);
                    half8 l2 = *(const half8*)(U + base + w12(s + d[2]) * 20);
                    half8 l3 = *(const half8*)(U + base + w12(s + d[3]) * 20);
                    af[mi] = (l0 + l1) + (l2 + l3);
                }
            }
            #pragma unroll
            for (int mi = 0; mi < 3; ++mi)
                #pragma unroll
                for (int nt = 0; nt < 4; ++nt)
                    acc[mi][nt] = __builtin_amdgcn_mfma_f32_16x16x32_f16(
                        af[mi], __builtin_bit_cast(half8, bw[nt]), acc[mi][nt], 0, 0, 0);
        }
    }
    __syncthreads();   // h1 + W2 reads done -> PART/POOLED overlays

    // ---------------- register pool partials: relu + sum4/max4 -> PART ----------------
    #pragma unroll
    for (int mi = 0; mi < 3; ++mi) {
        const int rr = 48 * wv + 16 * mi + 4 * quad;   // 4 rows, all within one b
        const int bq = rr / 12;
        const int chk = (rr - 12 * bq) >> 2;
        #pragma unroll
        for (int nt = 0; nt < 4; ++nt) {
            const int ch = nt * 16 + n;
            float r0 = fmaxf(acc[mi][nt][0], 0.f), r1 = fmaxf(acc[mi][nt][1], 0.f);
            float r2 = fmaxf(acc[mi][nt][2], 0.f), r3 = fmaxf(acc[mi][nt][3], 0.f);
            float sm = (r0 + r1) + (r2 + r3);
            float mx = fmaxf(fmaxf(r0, r1), fmaxf(r2, r3));
            U[(bq * 64 + ch) * 3 + chk] = cvtpk(sm, mx);
        }
    }
    // PART write->read is intra-wave (writer bq-range [4wv,4wv+3] == reader b = t>>4):
    // DS ops complete in order per wave; only prevent compiler reordering.
    __builtin_amdgcn_wave_barrier();

    // ---------------- pool-final: 3 b128 reads, f16 combine -> POOLED ----------------
    {
        const unsigned* p = U + t * 12;                // units 4t..4t+3
        uint4v q0 = *(const uint4v*)(p);
        uint4v q1 = *(const uint4v*)(p + 4);
        uint4v q2 = *(const uint4v*)(p + 8);
        unsigned arr[12] = {q0.x, q0.y, q0.z, q0.w, q1.x, q1.y, q1.z, q1.w,
                            q2.x, q2.y, q2.z, q2.w};
        const int b = t >> 4, ch0 = (t * 4) & 63;
        const _Float16 inv12 = (_Float16)(1.0f / 12.0f);
        unsigned pk[4];
        #pragma unroll
        for (int j = 0; j < 4; ++j) {
            half2v d0 = u2h(arr[3 * j]), d1 = u2h(arr[3 * j + 1]), d2 = u2h(arr[3 * j + 2]);
            _Float16 s = (d0[0] + d1[0]) + d2[0];
            _Float16 m0 = d0[1] > d1[1] ? d0[1] : d1[1];
            _Float16 m  = m0 > d2[1] ? m0 : d2[1];
            half2v pm;
            pm[0] = s * inv12;
            pm[1] = m;
            pk[j] = __builtin_bit_cast(unsigned, pm);
        }
        uint2 w01 = make_uint2(pk[0], pk[1]), w23 = make_uint2(pk[2], pk[3]);
        *(uint2*)(U + O_POOLDW + b * 68 + ch0)     = w01;
        *(uint2*)(U + O_POOLDW + b * 68 + ch0 + 2) = w23;
    }
    __syncthreads();

    // ---------------- fc1: MFMA (M=32, K=128, N=64), one 16x16 tile per wave -------
    {
        floatx4 a1 = (floatx4){bias1, bias1, bias1, bias1};
        const uint4v* f1q = (const uint4v*)(ws + (size_t)l * WSL + 6656);
        #pragma unroll
        for (int ks = 0; ks < 4; ++ks) {
            half8 av = *(const half8*)(USH + O_POOLUS + (mt * 16 + n) * 136 + ks * 32 + quad * 8);
            uint4v bw = f1q[oc * 17 + ks * 4 + quad];
            a1 = __builtin_amdgcn_mfma_f32_16x16x32_f16(av, __builtin_bit_cast(half8, bw), a1, 0, 0, 0);
        }
        #pragma unroll
        for (int i = 0; i < 2; ++i) {
            unsigned pk = cvtpk(fmaxf(a1[2 * i], 0.f), fmaxf(a1[2 * i + 1], 0.f));
            USH[O_POOL2 + (mt * 16 + quad * 4 + 2 * i)     * 72 + oc] = (unsigned short)(pk & 0xffffu);
            USH[O_POOL2 + (mt * 16 + quad * 4 + 2 * i + 1) * 72 + oc] = (unsigned short)(pk >> 16);
        }
    }
    __syncthreads();

    // ---------------- fc2: MFMA (M=32, K=64, N=64), one 16x16 tile per wave --------
    {
        floatx4 a2 = (floatx4){bias2, bias2, bias2, bias2};
        const uint4v* f2q = (const uint4v*)(ws + (size_t)l * WSL + 15360);
        #pragma unroll
        for (int ks = 0; ks < 2; ++ks) {
            half8 av = *(const half8*)(USH + O_POOL2 + (mt * 16 + n) * 72 + ks * 32 + quad * 8);
            uint4v bw = f2q[oc * 9 + ks * 4 + quad];
            a2 = __builtin_amdgcn_mfma_f32_16x16x32_f16(av, __builtin_bit_cast(half8, bw), a2, 0, 0, 0);
        }
        #pragma unroll
        for (int i = 0; i < 2; ++i) {
            unsigned pk = cvtpk(fmaxf(a2[2 * i], 0.f), fmaxf(a2[2 * i + 1], 0.f));
            USH[O_G2 + (mt * 16 + quad * 4 + 2 * i)     * 72 + oc] = (unsigned short)(pk & 0xffffu);
            USH[O_G2 + (mt * 16 + quad * 4 + 2 * i + 1) * 72 + oc] = (unsigned short)(pk >> 16);
        }
    }
    __syncthreads();

    // ---------------- fc3 (K=64) + output ----------------
    if (t < 32) {
        float a = fb3[l];
        const float* w3 = fw3 + (size_t)l * 64;
        #pragma unroll
        for (int c4 = 0; c4 < 16; ++c4) {
            uint2 u2 = *(const uint2*)(USH + O_G2 + t * 72 + c4 * 4);
            float4 w = *(const float4*)(w3 + c4 * 4);
            a += hlo16((unsigned short)(u2.x & 0xffff)) * w.x
               + hlo16((unsigned short)(u2.x >> 16))    * w.y
               + hlo16((unsigned short)(u2.y & 0xffff)) * w.z
               + hlo16((unsigned short)(u2.y >> 16))    * w.w;
        }
        out[(size_t)(b0 + t) * LNUM + l] = a;
    }
}

extern "C" void kernel_launch(void* const* d_in, const int* in_sizes, int n_in,
                              void* d_out, int out_size, void* d_ws, size_t ws_size,
                              hipStream_t stream) {
    const float* zs  = (const float*)d_in[0];
    const float* w1  = (const float*)d_in[1];
    const float* w2  = (const float*)d_in[2];
    const float* fw1 = (const float*)d_in[3];
    const float* fb1 = (const float*)d_in[4];
    const float* fw2 = (const float*)d_in[5];
    const float* fb2 = (const float*)d_in[6];
    const float* fw3 = (const float*)d_in[7];
    const float* fb3 = (const float*)d_in[8];
    float* out = (float*)d_out;
    unsigned short* ws = (unsigned short*)d_ws;

    hipLaunchKernelGGL(prep, dim3(LNUM, 3), dim3(256), 0, stream, w2, fw1, fw2, ws);
    hipLaunchKernelGGL(fused_nn, dim3(LNUM * NBT), dim3(512), 0, stream,
                       zs, w1, fb1, fb2, fw3, fb3, ws, out);
}